// Round 13
// baseline (114.528 us; speedup 1.0000x reference)
//
#include <hip/hip_runtime.h>
#include <hip/hip_bf16.h>
#include <math.h>

#define B_    8
#define N_    9225
#define M_    4096
#define K_    32
#define HID_  64
#define DOUT_ 16

typedef __attribute__((ext_vector_type(8))) short short8;
typedef __attribute__((ext_vector_type(4))) float floatx4;
typedef __attribute__((ext_vector_type(2))) float f32x2;
typedef __attribute__((ext_vector_type(4))) unsigned uint4v;
typedef __attribute__((ext_vector_type(16))) float f32x16;

static __device__ __forceinline__ short f2bf(float f) {
    __hip_bfloat16 h = __float2bfloat16(f);
    return __builtin_bit_cast(short, h);
}
static __device__ __forceinline__ f32x2 splat2(float v) { return (f32x2){v, v}; }

static __device__ __forceinline__ unsigned cvtpk(float a, float b) {
    unsigned r;
    asm("v_cvt_pk_bf16_f32 %0, %1, %2" : "=v"(r) : "v"(a), "v"(b));
    return r;
}
static __device__ __forceinline__ float pk_lo_f(unsigned u) {
    return __builtin_bit_cast(float, u << 16);
}
static __device__ __forceinline__ float pk_hi_f(unsigned u) {
    return __builtin_bit_cast(float, u & 0xffff0000u);
}

static __device__ __forceinline__ void gload_lds16(const float* g, float* lds_base) {
    __builtin_amdgcn_global_load_lds(
        (const __attribute__((address_space(1))) void*)g,
        (__attribute__((address_space(3))) void*)lds_base, 16, 0, 0);
}

// Sum over each 16-lane DPP row; lane (group*16+15) holds the group sum.
static __device__ __forceinline__ float row16_sum(float v) {
    int t;
    t = __builtin_amdgcn_update_dpp(0, __builtin_bit_cast(int, v), 0x111, 0xF, 0xF, true);
    v += __builtin_bit_cast(float, t);
    t = __builtin_amdgcn_update_dpp(0, __builtin_bit_cast(int, v), 0x112, 0xF, 0xF, true);
    v += __builtin_bit_cast(float, t);
    t = __builtin_amdgcn_update_dpp(0, __builtin_bit_cast(int, v), 0x114, 0xF, 0xF, true);
    v += __builtin_bit_cast(float, t);
    t = __builtin_amdgcn_update_dpp(0, __builtin_bit_cast(int, v), 0x118, 0xF, 0xF, true);
    v += __builtin_bit_cast(float, t);
    return v;
}

// R24: phase-geometry attack. Cross-round invariant: per-phase CU cost is
// ~350-400 cyc (283 compute-only) regardless of instruction mix (R13-R23:
// VALU 80-220 instrs/phase, occupancy 30-50%, ILP 1-2x -- all ~1us each).
// Only ~220 of 283 cyc are issue-attributable -> ~100 cyc/phase of fixed
// overhead + chain turnarounds. Lever: HALVE PHASE COUNT via 32-column
// phases (mfma_f32_32x32x16_bf16): each phase = 2 rows x 16 nbrs (cols
// 0-15 row A, 16-31 row B; per-column x makes this legal). 4 phases/wave
// (was 8). Layer-1 = 2 MFMAs (A = 128*W1^T replicated hi/lo at k=0..7,
// zero on hi-lanes), layer-2 = 4 (2 indep chains + add). C/D layout (guide-
// verified m74/m101): col=lane&31, row=(reg&3)+8*(reg>>2)+4*hi. Hidden-unit
// permutation absorbed in W2 A-frag: H = (jj&3)+8*((2m+(jj>>2))&3)+4hi+
// 32*(m>>1) (bijective over lane-held set). fv slab chunks ch=4hi+{0-3,
// 8-11} match the valid out rows (reg 0..7). DPP row16 reduce maps onto
// the 4 (row x hi) 16-lane quadrants natively. LUT gelu, hi/lo k-packing,
// burst+slab+sched_barrier, XCD pin all frozen from R23.
__global__ __launch_bounds__(256, 3) void it_kernel(
    const float* __restrict__ y,
    const float* __restrict__ x,
    const float* __restrict__ f_y,
    const float* __restrict__ weights,
    const float* __restrict__ W1,   // [4][64] row-major
    const float* __restrict__ b1,   // [64]
    const float* __restrict__ W2,   // [64][16] row-major
    const float* __restrict__ b2,   // [16]
    const int*   __restrict__ nbr,  // [B][M][K] int32
    float*       __restrict__ out)  // [B][M][16]
{
    __shared__ unsigned short lut[2048];       // 4KB gelu table
    __shared__ float stg[4][4][2][256];        // 32KB: wave x phase x chunk x lane*4

    const int tid  = threadIdx.x;
    #pragma unroll
    for (int i = tid; i < 2048; i += 256) {
        const float xi = (float)(i - 1024) * 0.0078125f;
        const float g  = 0.5f * xi * (1.0f + erff(xi * 0.70710678f));
        lut[i] = (unsigned short)f2bf(g);
    }

    const int lane = tid & 63;
    const int col  = lane & 31;        // MFMA column = neighbor slot
    const int hi   = lane >> 5;        // half-wave
    const int nlo  = lane & 15;
    const int rsel = (lane >> 4) & 1;  // which row of the pair this col serves

    const int blk   = blockIdx.x;
    const int batch = blk & 7;          // XCD pin
    const int pblk  = blk >> 3;
    const int wid   = tid >> 6;
    const int row0  = __builtin_amdgcn_readfirstlane(batch * M_ + pblk * 16 + wid * 4);
    const int bbase = batch * N_;

    // ---- neighbor indices, 4 phases: phase p = rows (2*(p>>1), +1), half p&1 ----
    int raw[4];
    #pragma unroll
    for (int p = 0; p < 4; ++p) {
        const int roff = 2 * (p >> 1) + rsel;
        const int kidx = (p & 1) * 16 + nlo;
        raw[p] = nbr[(size_t)(row0 + roff) * K_ + kidx];
    }

    // ---- layer-1 A-frags: A[hid=col][k=hi*8+jj]; hi=0 lanes hold 128*W1
    //      (hi inputs k=0..3, lo k=4..7, same weights); hi=1 lanes zero ----
    short8 w1a[2];
    #pragma unroll
    for (int t = 0; t < 2; ++t)
        #pragma unroll
        for (int jj = 0; jj < 8; ++jj) {
            const float wv = W1[(jj & 3) * HID_ + t * 32 + col] * 128.0f;
            w1a[t][jj] = (hi == 0) ? f2bf(wv) : (short)0;
        }

    // ---- layer-2 A-frags (4 MFMAs): A[out=col][k=hi*8+jj] = W2[H][out] ----
    short8 w2a[4];
    #pragma unroll
    for (int m = 0; m < 4; ++m)
        #pragma unroll
        for (int jj = 0; jj < 8; ++jj) {
            const int H = (jj & 3) + 8 * ((2 * m + (jj >> 2)) & 3) + 4 * hi + 32 * (m >> 1);
            w2a[m][jj] = (col < 16) ? f2bf(W2[H * DOUT_ + col]) : (short)0;
        }

    // ---- layer-1 C operand: LUT-index bias 128*b1+1024.5 at D layout ----
    f32x16 biasC[2];
    #pragma unroll
    for (int t = 0; t < 2; ++t)
        #pragma unroll
        for (int reg = 0; reg < 16; ++reg)
            biasC[t][reg] = b1[t * 32 + (reg & 3) + 8 * (reg >> 2) + 4 * hi] * 128.0f + 1024.5f;

    // ---- layer-2 C operand: b2 at valid rows (reg 0..7), else 0 ----
    f32x16 b2C;
    #pragma unroll
    for (int reg = 0; reg < 16; ++reg)
        b2C[reg] = (reg < 8) ? b2[(reg & 3) + 8 * (reg >> 2) + 4 * hi] : 0.0f;
    f32x16 zero16;
    #pragma unroll
    for (int reg = 0; reg < 16; ++reg) zero16[reg] = 0.0f;

    // ---- per-row x hi/lo packed words (4 rows) ----
    unsigned xw_h[4], xw_l[4];
    #pragma unroll
    for (int it = 0; it < 4; ++it) {
        const float2 xv = *(const float2*)(x + (size_t)(row0 + it) * 2);
        const unsigned hw_ = cvtpk(xv.x, xv.y);
        xw_h[it] = hw_;
        xw_l[it] = cvtpk(xv.x - pk_lo_f(hw_), xv.y - pk_hi_f(hw_));
    }

    // ---- BURST: fv -> LDS slab (2 chunks/phase: ch 4hi+0..3, 4hi+8..11);
    //      w -> regs; y (hi=0 lanes only) -> regs, zero-init ----
    float2 yv[4]; float sw[4];
    #pragma unroll
    for (int i = 0; i < 4; ++i) yv[i] = (float2){0.0f, 0.0f};
    #pragma unroll
    for (int p = 0; p < 4; ++p) {
        const int rv = raw[p];
        const int bn = bbase + (rv >= 0 ? rv : 0);
        gload_lds16(f_y + (size_t)bn * 16 + 4 * hi,     &stg[wid][p][0][0]);
        gload_lds16(f_y + (size_t)bn * 16 + 4 * hi + 8, &stg[wid][p][1][0]);
        const float wv_ = weights[bn];
        sw[p] = (rv >= 0) ? wv_ : 0.0f;
        if (lane < 32) yv[p] = *(const float2*)(y + (size_t)bn * 2);
    }
    __syncthreads();
    __builtin_amdgcn_sched_barrier(0);

    // ---- pre-convert y hi/lo words (finite zeros on hi=1 lanes) ----
    unsigned ywh[4], ywl[4];
    #pragma unroll
    for (int p = 0; p < 4; ++p) {
        const float y0 = yv[p].x, y1 = yv[p].y;
        const unsigned hw_ = cvtpk(y0, y1);
        ywh[p] = hw_;
        ywl[p] = cvtpk(y0 - pk_lo_f(hw_), y1 - pk_hi_f(hw_));
    }

    float partial[8] = {0.f, 0.f, 0.f, 0.f, 0.f, 0.f, 0.f, 0.f};
    #pragma unroll
    for (int p = 0; p < 4; ++p) {
        const int rA = 2 * (p >> 1);

        // ---- B-frag: k=0..7 (hi-lanes' k=8..15 hit A==0) ----
        const unsigned xh_ = rsel ? xw_h[rA + 1] : xw_h[rA];
        const unsigned xl_ = rsel ? xw_l[rA + 1] : xw_l[rA];
        const uint4v bwv = { ywh[p], xh_, ywl[p], xl_ };
        const short8 bf = __builtin_bit_cast(short8, bwv);

        // ---- layer 1: 2 independent MFMAs; a1[t][reg] IS the LUT index ----
        const f32x16 a1lo = __builtin_amdgcn_mfma_f32_32x32x16_bf16(w1a[0], bf, biasC[0], 0, 0, 0);
        const f32x16 a1hi = __builtin_amdgcn_mfma_f32_32x32x16_bf16(w1a[1], bf, biasC[1], 0, 0, 0);

        // fv chunks (own slot: lane*16B, conflict-free), pre-scaled by w
        const floatx4 fv0 = *(const floatx4*)&stg[wid][p][0][lane * 4];
        const floatx4 fv1 = *(const floatx4*)&stg[wid][p][1][lane * 4];
        const float s = sw[p];
        const floatx4 g0 = fv0 * s, g1 = fv1 * s;

        // ---- gelu LUT -> layer-2 B-frags. For MFMA m, word w:
        //      t=m>>1, u=(2m+(w>>1))&3, regA=(u<<2)|((2w)&3), regB=regA+1 ----
        short8 bm[4];
        #pragma unroll
        for (int m = 0; m < 4; ++m) {
            unsigned words[4];
            #pragma unroll
            for (int w = 0; w < 4; ++w) {
                const int t    = m >> 1;
                const int u    = (2 * m + (w >> 1)) & 3;
                const int regA = (u << 2) | ((2 * w) & 3);
                const float iA = t ? a1hi[regA]     : a1lo[regA];
                const float iB = t ? a1hi[regA + 1] : a1lo[regA + 1];
                f32x2 iv = {iA, iB};
                iv = __builtin_elementwise_min(
                         __builtin_elementwise_max(iv, splat2(0.0f)), splat2(2047.0f));
                const unsigned short lA = lut[(unsigned)iv[0]];
                const unsigned short lB = lut[(unsigned)iv[1]];
                words[w] = (unsigned)lA | ((unsigned)lB << 16);
            }
            bm[m] = __builtin_bit_cast(short8, (uint4v){words[0], words[1], words[2], words[3]});
        }

        // ---- layer 2: two independent 2-chains, then add ----
        f32x16 acc01 = __builtin_amdgcn_mfma_f32_32x32x16_bf16(w2a[0], bm[0], b2C, 0, 0, 0);
        f32x16 acc23 = __builtin_amdgcn_mfma_f32_32x32x16_bf16(w2a[2], bm[2], zero16, 0, 0, 0);
        acc01 = __builtin_amdgcn_mfma_f32_32x32x16_bf16(w2a[1], bm[1], acc01, 0, 0, 0);
        acc23 = __builtin_amdgcn_mfma_f32_32x32x16_bf16(w2a[3], bm[3], acc23, 0, 0, 0);

        // ---- accumulate valid rows (reg 0..7): ch = 4hi + (r&3) + 8*(r>>2) ----
        #pragma unroll
        for (int r = 0; r < 4; ++r) {
            partial[r]     = fmaf(acc01[r]     + acc23[r],     g0[r], partial[r]);
            partial[4 + r] = fmaf(acc01[4 + r] + acc23[4 + r], g1[r], partial[4 + r]);
        }

        if (p & 1) {   // both halves of the row pair done: reduce + store
            #pragma unroll
            for (int r = 0; r < 8; ++r) partial[r] = row16_sum(partial[r]);
            if (nlo == 15) {
                const int row = row0 + rA + rsel;
                floatx4 o0 = {partial[0], partial[1], partial[2], partial[3]};
                floatx4 o1 = {partial[4], partial[5], partial[6], partial[7]};
                *(floatx4*)(out + (size_t)row * DOUT_ + 4 * hi)     = o0;
                *(floatx4*)(out + (size_t)row * DOUT_ + 4 * hi + 8) = o1;
            }
            #pragma unroll
            for (int r = 0; r < 8; ++r) partial[r] = 0.f;
        }
    }
}

extern "C" void kernel_launch(void* const* d_in, const int* in_sizes, int n_in,
                              void* d_out, int out_size, void* d_ws, size_t ws_size,
                              hipStream_t stream) {
    const float* y   = (const float*)d_in[0];
    const float* x   = (const float*)d_in[1];
    const float* f_y = (const float*)d_in[2];
    const float* w   = (const float*)d_in[3];
    const float* W1  = (const float*)d_in[4];
    const float* b1  = (const float*)d_in[5];
    const float* W2  = (const float*)d_in[6];
    const float* b2  = (const float*)d_in[7];
    const int*   nbr = (const int*)d_in[8];
    float* out = (float*)d_out;

    // Single dispatch. 2048 blocks: 256 per batch (16 rows/block),
    // batch = blk & 7 -> XCD pin.
    dim3 grid(B_ * M_ / 16), block(256);
    hipLaunchKernelGGL(it_kernel, grid, block, 0, stream,
                       y, x, f_y, w, W1, b1, W2, b2, nbr, out);
}

// Round 14
// 102.541 us; speedup vs baseline: 1.1169x; 1.1169x over previous
//
#include <hip/hip_runtime.h>
#include <hip/hip_bf16.h>
#include <math.h>

#define B_    8
#define N_    9225
#define M_    4096
#define K_    32
#define HID_  64
#define DOUT_ 16

typedef __attribute__((ext_vector_type(8))) short short8;
typedef __attribute__((ext_vector_type(4))) float floatx4;
typedef __attribute__((ext_vector_type(2))) float f32x2;
typedef __attribute__((ext_vector_type(4))) unsigned uint4v;

static __device__ __forceinline__ short f2bf(float f) {
    __hip_bfloat16 h = __float2bfloat16(f);
    return __builtin_bit_cast(short, h);
}
static __device__ __forceinline__ f32x2 splat2(float v) { return (f32x2){v, v}; }

static __device__ __forceinline__ unsigned cvtpk(float a, float b) {
    unsigned r;
    asm("v_cvt_pk_bf16_f32 %0, %1, %2" : "=v"(r) : "v"(a), "v"(b));
    return r;
}
static __device__ __forceinline__ float pk_lo_f(unsigned u) {
    return __builtin_bit_cast(float, u << 16);
}
static __device__ __forceinline__ float pk_hi_f(unsigned u) {
    return __builtin_bit_cast(float, u & 0xffff0000u);
}

// Scattered gather DIRECT to LDS: global source address is per-lane; LDS
// dest is the wave-uniform slab base -- HW writes base + lane*16.
static __device__ __forceinline__ void gload_lds16(const float* g, float* lds_base) {
    __builtin_amdgcn_global_load_lds(
        (const __attribute__((address_space(1))) void*)g,
        (__attribute__((address_space(3))) void*)lds_base, 16, 0, 0);
}

// Sum over each 16-lane DPP row via row_shr tree; lane (row*16+15) holds the sum.
static __device__ __forceinline__ float row16_sum(float v) {
    int t;
    t = __builtin_amdgcn_update_dpp(0, __builtin_bit_cast(int, v), 0x111, 0xF, 0xF, true);
    v += __builtin_bit_cast(float, t);
    t = __builtin_amdgcn_update_dpp(0, __builtin_bit_cast(int, v), 0x112, 0xF, 0xF, true);
    v += __builtin_bit_cast(float, t);
    t = __builtin_amdgcn_update_dpp(0, __builtin_bit_cast(int, v), 0x114, 0xF, 0xF, true);
    v += __builtin_bit_cast(float, t);
    t = __builtin_amdgcn_update_dpp(0, __builtin_bit_cast(int, v), 0x118, 0xF, 0xF, true);
    v += __builtin_bit_cast(float, t);
    return v;
}

// R25 == R23 (verified session best, 102.4us): locked in after R24's 32x32
// phase-widening regressed to 114.5 (VGPR cap 84 << ~200 needed -> compiler
// rematerialized f32x16 constants and serialized the chains; plus first
// direct sighting of the gelu-LUT's inherent LDS bank conflicts, 1.86M/
// dispatch ~ 1.9 extra cyc/read -- present invisibly since R21 and why the
// LUT only netted ~1us over Pade). Session ledger: compute-only floor
// ~27-30us (R19-V1 ablation), gathers ~7-10us; every surviving lever (VALU
// +-30%, occupancy 30-50%, addresses 144->80, burst+sched_barrier, cvt_pk,
// LUT gelu, slab staging, 2-chain ILP, 32-col phases) lands within +-1us of
// it_kernel ~37us. Binder: the per-eval gelu-index dependency chain (3 VALU
// + 1 conflicted LDS read x 64M evals) at ~2.5 waves/SIMD residency -- a
// structural local optimum, not a HW roofline (no counter saturated).
// Structure: 2048 blocks (XCD-pinned batch=blk&7), 4 rows/wave, burst
// gathers (fv via global_load_lds slab, y q0-masked, w per-lane), erf-gelu
// LDS LUT with W1 pre-scaled 128 + bias-as-C (a1 IS the LUT index), hi/lo
// k-packed layer-1, re-indexed W2 frag, per-row dual-chain interleave.
__global__ __launch_bounds__(256, 3) void it_kernel(
    const float* __restrict__ y,
    const float* __restrict__ x,
    const float* __restrict__ f_y,
    const float* __restrict__ weights,
    const float* __restrict__ W1,   // [4][64] row-major
    const float* __restrict__ b1,   // [64]
    const float* __restrict__ W2,   // [64][16] row-major
    const float* __restrict__ b2,   // [16]
    const int*   __restrict__ nbr,  // [B][M][K] int32
    float*       __restrict__ out)  // [B][M][16]
{
    __shared__ unsigned short lut[2048];        // 4KB gelu table
    __shared__ float stg[4][8][256];            // 32KB: wave x phase x lane*4

    const int tid  = threadIdx.x;
    // ---- fill gelu LUT: exact erf-gelu, bf16 values. [-8,8], step 1/128 ----
    #pragma unroll
    for (int i = tid; i < 2048; i += 256) {
        const float xi = (float)(i - 1024) * 0.0078125f;
        const float g  = 0.5f * xi * (1.0f + erff(xi * 0.70710678f));
        lut[i] = (unsigned short)f2bf(g);
    }

    const int lane = tid & 63;
    const int q    = lane >> 4;    // quad 0..3
    const int nlo  = lane & 15;
    const bool q0  = (q == 0);

    const int blk   = blockIdx.x;
    const int batch = blk & 7;          // XCD pin (round-robin heuristic)
    const int pblk  = blk >> 3;         // 0..255 within batch
    const int wid   = tid >> 6;         // wave 0..3
    const int row0  = __builtin_amdgcn_readfirstlane(batch * M_ + pblk * 16 + wid * 4);
    const int bbase = batch * N_;

    // ---- neighbor indices for all 8 phases: issue first ----
    int raw[8];
    #pragma unroll
    for (int ph = 0; ph < 8; ++ph) {
        const int it = ph >> 1, h = ph & 1;
        raw[ph] = nbr[(size_t)(row0 + it) * K_ + h * 16 + nlo];
    }

    // ---- W1^T A-fragments, hi/lo k-packed, pre-scaled by 128 (exact pow2) ----
    short8 w1h[4];
    #pragma unroll
    for (int t = 0; t < 4; ++t) {
        #pragma unroll
        for (int jj = 0; jj < 4; ++jj) {
            const float wv = W1[jj * HID_ + t * 16 + nlo] * 128.0f;
            const short b  = q0 ? f2bf(wv) : (short)0;
            w1h[t][jj]     = b;
            w1h[t][jj + 4] = b;
        }
    }

    // ---- W2 A-fragment with layer-1-layout re-index (R13-validated) ----
    short8 w2f[2];
    #pragma unroll
    for (int ch = 0; ch < 2; ++ch)
        #pragma unroll
        for (int jj = 0; jj < 8; ++jj) {
            const int H = (ch * 2 + (jj >> 2)) * 16 + q * 4 + (jj & 3);
            w2f[ch][jj] = f2bf(W2[H * DOUT_ + nlo]);
        }

    // ---- LUT-index bias as layer-1 MFMA C operand: 128*b1 + 1024.5 ----
    floatx4 biasC[4];
    #pragma unroll
    for (int t = 0; t < 4; ++t) {
        const floatx4 b1q = *(const floatx4*)(b1 + t * 16 + q * 4);
        biasC[t] = b1q * 128.0f + 1024.5f;
    }
    const floatx4 b2r = *(const floatx4*)(b2 + q * 4);

    // ---- per-row x hi/lo, packed words (4 rows) ----
    unsigned xw_h[4], xw_l[4];
    #pragma unroll
    for (int it = 0; it < 4; ++it) {
        const float2 xv = *(const float2*)(x + (size_t)(row0 + it) * 2);
        const unsigned hw = cvtpk(xv.x, xv.y);
        xw_h[it] = hw;
        xw_l[it] = cvtpk(xv.x - pk_lo_f(hw), xv.y - pk_hi_f(hw));
    }

    // ---- BURST: fv -> LDS slab (no VGPR cost), y/w -> regs ----
    float2 yv2[8]; float sw[8];
    #pragma unroll
    for (int i = 0; i < 8; ++i) yv2[i] = (float2){0.0f, 0.0f};
    #pragma unroll
    for (int P = 0; P < 8; ++P) {
        const int rv  = raw[P];
        const int vld = rv >= 0;
        const int bn  = bbase + (vld ? rv : 0);
        gload_lds16(f_y + (size_t)bn * 16 + q * 4, &stg[wid][P][0]);
        const float wv_ = weights[bn];
        sw[P] = vld ? wv_ : 0.0f;
        if (q0) yv2[P] = *(const float2*)(y + (size_t)bn * 2);
    }

    // Single drain: __syncthreads waits vmcnt(0)+lgkmcnt(0) (burst + y/w
    // complete, LUT visible). sched_barrier keeps compute below it.
    __syncthreads();
    __builtin_amdgcn_sched_barrier(0);

    // ---- pre-convert ALL phases' y hi/lo words (hoisted off the chains) ----
    unsigned yw_h8[8], yw_l8[8];
    #pragma unroll
    for (int P = 0; P < 8; ++P) {
        const float y0 = yv2[P].x, y1 = yv2[P].y;
        const unsigned hw_ = cvtpk(y0, y1);
        yw_h8[P] = hw_;
        yw_l8[P] = cvtpk(y0 - pk_lo_f(hw_), y1 - pk_hi_f(hw_));
    }

    float partial[4] = {0.f, 0.f, 0.f, 0.f};
    #pragma unroll
    for (int it = 0; it < 4; ++it) {
        const int pa = 2 * it, pb = 2 * it + 1;

        // fv slices for both half-phases (ds_read_b128, issued up front)
        const floatx4 fva = *(const floatx4*)&stg[wid][pa][lane * 4];
        const floatx4 fvb = *(const floatx4*)&stg[wid][pb][lane * 4];

        // ---- both B-fragments (pure bit assembly from precomputed words) ----
        const uint4v bwa = { yw_h8[pa], xw_h[it], yw_l8[pa], xw_l[it] };
        const uint4v bwb = { yw_h8[pb], xw_h[it], yw_l8[pb], xw_l[it] };
        const short8 bfa = __builtin_bit_cast(short8, bwa);
        const short8 bfb = __builtin_bit_cast(short8, bwb);

        // ---- layer 1, two independent chains interleaved ----
        floatx4 a1a[4], a1b[4];
        #pragma unroll
        for (int t = 0; t < 4; ++t) {
            a1a[t] = __builtin_amdgcn_mfma_f32_16x16x32_bf16(w1h[t], bfa, biasC[t], 0, 0, 0);
            a1b[t] = __builtin_amdgcn_mfma_f32_16x16x32_bf16(w1h[t], bfb, biasC[t], 0, 0, 0);
        }

        // ---- gelu LUT for both chains, interleaved ----
        unsigned hwa[8], hwb[8];
        #pragma unroll
        for (int t = 0; t < 4; ++t) {
            f32x2 ia01 = {a1a[t][0], a1a[t][1]}, ia23 = {a1a[t][2], a1a[t][3]};
            f32x2 ib01 = {a1b[t][0], a1b[t][1]}, ib23 = {a1b[t][2], a1b[t][3]};
            ia01 = __builtin_elementwise_min(
                       __builtin_elementwise_max(ia01, splat2(0.0f)), splat2(2047.0f));
            ia23 = __builtin_elementwise_min(
                       __builtin_elementwise_max(ia23, splat2(0.0f)), splat2(2047.0f));
            ib01 = __builtin_elementwise_min(
                       __builtin_elementwise_max(ib01, splat2(0.0f)), splat2(2047.0f));
            ib23 = __builtin_elementwise_min(
                       __builtin_elementwise_max(ib23, splat2(0.0f)), splat2(2047.0f));
            const unsigned short a0 = lut[(unsigned)ia01[0]];
            const unsigned short a1v = lut[(unsigned)ia01[1]];
            const unsigned short a2 = lut[(unsigned)ia23[0]];
            const unsigned short a3 = lut[(unsigned)ia23[1]];
            const unsigned short c0 = lut[(unsigned)ib01[0]];
            const unsigned short c1 = lut[(unsigned)ib01[1]];
            const unsigned short c2 = lut[(unsigned)ib23[0]];
            const unsigned short c3 = lut[(unsigned)ib23[1]];
            hwa[t * 2 + 0] = (unsigned)a0 | ((unsigned)a1v << 16);
            hwa[t * 2 + 1] = (unsigned)a2 | ((unsigned)a3 << 16);
            hwb[t * 2 + 0] = (unsigned)c0 | ((unsigned)c1 << 16);
            hwb[t * 2 + 1] = (unsigned)c2 | ((unsigned)c3 << 16);
        }
        const short8 hf0a = __builtin_bit_cast(short8, (uint4v){hwa[0], hwa[1], hwa[2], hwa[3]});
        const short8 hf1a = __builtin_bit_cast(short8, (uint4v){hwa[4], hwa[5], hwa[6], hwa[7]});
        const short8 hf0b = __builtin_bit_cast(short8, (uint4v){hwb[0], hwb[1], hwb[2], hwb[3]});
        const short8 hf1b = __builtin_bit_cast(short8, (uint4v){hwb[4], hwb[5], hwb[6], hwb[7]});

        // ---- layer 2, both chains interleaved ----
        floatx4 acca = b2r, accb = b2r;
        acca = __builtin_amdgcn_mfma_f32_16x16x32_bf16(w2f[0], hf0a, acca, 0, 0, 0);
        accb = __builtin_amdgcn_mfma_f32_16x16x32_bf16(w2f[0], hf0b, accb, 0, 0, 0);
        acca = __builtin_amdgcn_mfma_f32_16x16x32_bf16(w2f[1], hf1a, acca, 0, 0, 0);
        accb = __builtin_amdgcn_mfma_f32_16x16x32_bf16(w2f[1], hf1b, accb, 0, 0, 0);

        // ---- accumulate both half-phases, reduce over 16 lanes, store row ----
        const float sa = sw[pa], sb = sw[pb];
        #pragma unroll
        for (int r = 0; r < 4; ++r) {
            partial[r] = fmaf(acca[r], fva[r] * sa, partial[r]);
            partial[r] = fmaf(accb[r], fvb[r] * sb, partial[r]);
        }
        #pragma unroll
        for (int r = 0; r < 4; ++r) partial[r] = row16_sum(partial[r]);
        if (nlo == 15) {
            floatx4 o = {partial[0], partial[1], partial[2], partial[3]};
            *(floatx4*)(out + (size_t)(row0 + it) * DOUT_ + q * 4) = o;
        }
        #pragma unroll
        for (int r = 0; r < 4; ++r) partial[r] = 0.f;
    }
}

extern "C" void kernel_launch(void* const* d_in, const int* in_sizes, int n_in,
                              void* d_out, int out_size, void* d_ws, size_t ws_size,
                              hipStream_t stream) {
    const float* y   = (const float*)d_in[0];
    const float* x   = (const float*)d_in[1];
    const float* f_y = (const float*)d_in[2];
    const float* w   = (const float*)d_in[3];
    const float* W1  = (const float*)d_in[4];
    const float* b1  = (const float*)d_in[5];
    const float* W2  = (const float*)d_in[6];
    const float* b2  = (const float*)d_in[7];
    const int*   nbr = (const int*)d_in[8];
    float* out = (float*)d_out;

    // Single dispatch. 2048 blocks: 256 per batch (16 rows/block),
    // batch = blk & 7 -> XCD pin.
    dim3 grid(B_ * M_ / 16), block(256);
    hipLaunchKernelGGL(it_kernel, grid, block, 0, stream,
                       y, x, f_y, w, W1, b1, W2, b2, nbr, out);
}

// Round 15
// 101.730 us; speedup vs baseline: 1.1258x; 1.0080x over previous
//
#include <hip/hip_runtime.h>
#include <hip/hip_bf16.h>
#include <math.h>

#define B_    8
#define N_    9225
#define M_    4096
#define K_    32
#define HID_  64
#define DOUT_ 16

typedef __attribute__((ext_vector_type(8))) short short8;
typedef __attribute__((ext_vector_type(4))) float floatx4;
typedef __attribute__((ext_vector_type(2))) float f32x2;
typedef __attribute__((ext_vector_type(4))) unsigned uint4v;

static __device__ __forceinline__ short f2bf(float f) {
    __hip_bfloat16 h = __float2bfloat16(f);
    return __builtin_bit_cast(short, h);
}
static __device__ __forceinline__ floatx4 splat4(float v) { return (floatx4){v, v, v, v}; }

// Scattered gather DIRECT to LDS: global source address is per-lane; LDS
// dest is the wave-uniform slab base -- HW writes base + lane*16.
static __device__ __forceinline__ void gload_lds16(const float* g, float* lds_base) {
    __builtin_amdgcn_global_load_lds(
        (const __attribute__((address_space(1))) void*)g,
        (__attribute__((address_space(3))) void*)lds_base, 16, 0, 0);
}

// Sum over each 16-lane DPP row via row_shr tree; lane (row*16+15) holds the sum.
static __device__ __forceinline__ float row16_sum(float v) {
    int t;
    t = __builtin_amdgcn_update_dpp(0, __builtin_bit_cast(int, v), 0x111, 0xF, 0xF, true);
    v += __builtin_bit_cast(float, t);
    t = __builtin_amdgcn_update_dpp(0, __builtin_bit_cast(int, v), 0x112, 0xF, 0xF, true);
    v += __builtin_bit_cast(float, t);
    t = __builtin_amdgcn_update_dpp(0, __builtin_bit_cast(int, v), 0x114, 0xF, 0xF, true);
    v += __builtin_bit_cast(float, t);
    t = __builtin_amdgcn_update_dpp(0, __builtin_bit_cast(int, v), 0x118, 0xF, 0xF, true);
    v += __builtin_bit_cast(float, t);
    return v;
}

// R26: rank-4 factorized layer-1 (VALU, exact f32). The 4->64 layer never
// needed MFMA: pre[H] = y0*W1[0][H] + y1*W1[1][H] + (x0*W1[2][H] +
// x1*W1[3][H] + b1[H]). Per lane, per phase: idx[t] = fma(y0, c0[t],
// fma(y1, c1[t], ax[row][t])) with c0/c1 = 128*W1[0/1] slices held in regs
// (32) and ax = per-row x/b1 part precomputed at setup (64 regs, exact f32,
// LUT scale+bias folded). Removes per phase: 4 MFMAs, y hi/lo bf16 cvt,
// B-frag assembly (~25 instrs + 2 MFMA-latency stages mid-chain); adds 16
// pk-FMAs with zero added chain depth (y reg-resident from burst). Layer-1
// quantization GONE (y,x,W1 exact f32) -> absmax <= 0.0625. MFMAs/phase
// 6 -> 2 (layer-2 only). Downstream frozen from R25 (verified best 102.4):
// erf-gelu LDS LUT (idx IS the a1 output), H-re-indexed W2 frag, fv via
// global_load_lds slab, burst+sched_barrier, dual-chain row pairs, DPP
// reduce, XCD pin. Pre-committed: null => per-phase cost is issue/
// scheduling-structural, declare terminal; regression => revert R25.
__global__ __launch_bounds__(256, 3) void it_kernel(
    const float* __restrict__ y,
    const float* __restrict__ x,
    const float* __restrict__ f_y,
    const float* __restrict__ weights,
    const float* __restrict__ W1,   // [4][64] row-major
    const float* __restrict__ b1,   // [64]
    const float* __restrict__ W2,   // [64][16] row-major
    const float* __restrict__ b2,   // [16]
    const int*   __restrict__ nbr,  // [B][M][K] int32
    float*       __restrict__ out)  // [B][M][16]
{
    __shared__ unsigned short lut[2048];        // 4KB gelu table
    __shared__ float stg[4][8][256];            // 32KB: wave x phase x lane*4

    const int tid  = threadIdx.x;
    // ---- fill gelu LUT: exact erf-gelu, bf16 values. [-8,8], step 1/128 ----
    #pragma unroll
    for (int i = tid; i < 2048; i += 256) {
        const float xi = (float)(i - 1024) * 0.0078125f;
        const float g  = 0.5f * xi * (1.0f + erff(xi * 0.70710678f));
        lut[i] = (unsigned short)f2bf(g);
    }

    const int lane = tid & 63;
    const int q    = lane >> 4;    // quad 0..3
    const int nlo  = lane & 15;

    const int blk   = blockIdx.x;
    const int batch = blk & 7;          // XCD pin (round-robin heuristic)
    const int pblk  = blk >> 3;         // 0..255 within batch
    const int wid   = tid >> 6;         // wave 0..3
    const int row0  = __builtin_amdgcn_readfirstlane(batch * M_ + pblk * 16 + wid * 4);
    const int bbase = batch * N_;

    // ---- neighbor indices for all 8 phases: issue first ----
    int raw[8];
    #pragma unroll
    for (int ph = 0; ph < 8; ++ph) {
        const int it = ph >> 1, h = ph & 1;
        raw[ph] = nbr[(size_t)(row0 + it) * K_ + h * 16 + nlo];
    }

    // ---- layer-1 weight slices for this lane's 16 H-slots (H = 16t+4q+r):
    //      c0/c1 = 128*W1[0/1][H] (y coefficients, exact f32) ----
    floatx4 c0q[4], c1q[4];
    #pragma unroll
    for (int t = 0; t < 4; ++t) {
        c0q[t] = *(const floatx4*)(W1 + 0 * HID_ + t * 16 + q * 4) * 128.0f;
        c1q[t] = *(const floatx4*)(W1 + 1 * HID_ + t * 16 + q * 4) * 128.0f;
    }

    // ---- per-row x/b1 part of the LUT index, exact f32, 4 rows:
    //      ax[it][t] = 128*(x0*W1[2][H] + x1*W1[3][H] + b1[H]) + 1024.5 ----
    floatx4 ax[4][4];
    #pragma unroll
    for (int t = 0; t < 4; ++t) {
        const floatx4 w2v = *(const floatx4*)(W1 + 2 * HID_ + t * 16 + q * 4);
        const floatx4 w3v = *(const floatx4*)(W1 + 3 * HID_ + t * 16 + q * 4);
        const floatx4 b1v = *(const floatx4*)(b1 + t * 16 + q * 4);
        #pragma unroll
        for (int it = 0; it < 4; ++it) {
            const float2 xv = *(const float2*)(x + (size_t)(row0 + it) * 2);
            const floatx4 pre = __builtin_elementwise_fma(splat4(xv.x), w2v,
                                __builtin_elementwise_fma(splat4(xv.y), w3v, b1v));
            ax[it][t] = __builtin_elementwise_fma(pre, splat4(128.0f), splat4(1024.5f));
        }
    }

    // ---- W2 A-fragment with layer-1-layout re-index (R13-validated) ----
    short8 w2f[2];
    #pragma unroll
    for (int ch = 0; ch < 2; ++ch)
        #pragma unroll
        for (int jj = 0; jj < 8; ++jj) {
            const int H = (ch * 2 + (jj >> 2)) * 16 + q * 4 + (jj & 3);
            w2f[ch][jj] = f2bf(W2[H * DOUT_ + nlo]);
        }
    const floatx4 b2r = *(const floatx4*)(b2 + q * 4);

    // ---- BURST: fv -> LDS slab (no VGPR cost); y (all lanes, f32) + w -> regs ----
    float2 yv2[8]; float sw[8];
    #pragma unroll
    for (int P = 0; P < 8; ++P) {
        const int rv  = raw[P];
        const int vld = rv >= 0;
        const int bn  = bbase + (vld ? rv : 0);
        gload_lds16(f_y + (size_t)bn * 16 + q * 4, &stg[wid][P][0]);
        const float wv_ = weights[bn];
        sw[P] = vld ? wv_ : 0.0f;
        yv2[P] = *(const float2*)(y + (size_t)bn * 2);   // finite garbage if invalid; killed by sw=0
    }

    // Single drain: __syncthreads waits vmcnt(0)+lgkmcnt(0) (burst complete,
    // LUT visible). sched_barrier keeps compute below it.
    __syncthreads();
    __builtin_amdgcn_sched_barrier(0);

    float partial[4] = {0.f, 0.f, 0.f, 0.f};
    #pragma unroll
    for (int it = 0; it < 4; ++it) {
        const int pa = 2 * it, pb = 2 * it + 1;

        // fv slices for both half-phases (ds_read_b128, issued up front)
        const floatx4 fva = *(const floatx4*)&stg[wid][pa][lane * 4];
        const floatx4 fvb = *(const floatx4*)&stg[wid][pb][lane * 4];

        const float y0a = yv2[pa].x, y1a = yv2[pa].y;
        const float y0b = yv2[pb].x, y1b = yv2[pb].y;

        // ---- layer 1 (rank-4, exact f32): idx = y0*c0 + y1*c1 + ax;
        //      then clamp -> LUT -> pack. Two independent chains. ----
        unsigned hwa[8], hwb[8];
        #pragma unroll
        for (int t = 0; t < 4; ++t) {
            floatx4 ia = __builtin_elementwise_fma(splat4(y0a), c0q[t],
                         __builtin_elementwise_fma(splat4(y1a), c1q[t], ax[it][t]));
            floatx4 ib = __builtin_elementwise_fma(splat4(y0b), c0q[t],
                         __builtin_elementwise_fma(splat4(y1b), c1q[t], ax[it][t]));
            ia = __builtin_elementwise_min(
                     __builtin_elementwise_max(ia, splat4(0.0f)), splat4(2047.0f));
            ib = __builtin_elementwise_min(
                     __builtin_elementwise_max(ib, splat4(0.0f)), splat4(2047.0f));
            const unsigned short a0 = lut[(unsigned)ia[0]];
            const unsigned short a1 = lut[(unsigned)ia[1]];
            const unsigned short a2 = lut[(unsigned)ia[2]];
            const unsigned short a3 = lut[(unsigned)ia[3]];
            const unsigned short c0 = lut[(unsigned)ib[0]];
            const unsigned short c1 = lut[(unsigned)ib[1]];
            const unsigned short c2 = lut[(unsigned)ib[2]];
            const unsigned short c3 = lut[(unsigned)ib[3]];
            hwa[t * 2 + 0] = (unsigned)a0 | ((unsigned)a1 << 16);
            hwa[t * 2 + 1] = (unsigned)a2 | ((unsigned)a3 << 16);
            hwb[t * 2 + 0] = (unsigned)c0 | ((unsigned)c1 << 16);
            hwb[t * 2 + 1] = (unsigned)c2 | ((unsigned)c3 << 16);
        }
        const short8 hf0a = __builtin_bit_cast(short8, (uint4v){hwa[0], hwa[1], hwa[2], hwa[3]});
        const short8 hf1a = __builtin_bit_cast(short8, (uint4v){hwa[4], hwa[5], hwa[6], hwa[7]});
        const short8 hf0b = __builtin_bit_cast(short8, (uint4v){hwb[0], hwb[1], hwb[2], hwb[3]});
        const short8 hf1b = __builtin_bit_cast(short8, (uint4v){hwb[4], hwb[5], hwb[6], hwb[7]});

        // ---- layer 2: both chains interleaved (only MFMAs left) ----
        floatx4 acca = b2r, accb = b2r;
        acca = __builtin_amdgcn_mfma_f32_16x16x32_bf16(w2f[0], hf0a, acca, 0, 0, 0);
        accb = __builtin_amdgcn_mfma_f32_16x16x32_bf16(w2f[0], hf0b, accb, 0, 0, 0);
        acca = __builtin_amdgcn_mfma_f32_16x16x32_bf16(w2f[1], hf1a, acca, 0, 0, 0);
        accb = __builtin_amdgcn_mfma_f32_16x16x32_bf16(w2f[1], hf1b, accb, 0, 0, 0);

        // ---- accumulate both half-phases, reduce over 16 lanes, store row ----
        const float sa = sw[pa], sb = sw[pb];
        #pragma unroll
        for (int r = 0; r < 4; ++r) {
            partial[r] = fmaf(acca[r], fva[r] * sa, partial[r]);
            partial[r] = fmaf(accb[r], fvb[r] * sb, partial[r]);
        }
        #pragma unroll
        for (int r = 0; r < 4; ++r) partial[r] = row16_sum(partial[r]);
        if (nlo == 15) {
            floatx4 o = {partial[0], partial[1], partial[2], partial[3]};
            *(floatx4*)(out + (size_t)(row0 + it) * DOUT_ + q * 4) = o;
        }
        #pragma unroll
        for (int r = 0; r < 4; ++r) partial[r] = 0.f;
    }
}

extern "C" void kernel_launch(void* const* d_in, const int* in_sizes, int n_in,
                              void* d_out, int out_size, void* d_ws, size_t ws_size,
                              hipStream_t stream) {
    const float* y   = (const float*)d_in[0];
    const float* x   = (const float*)d_in[1];
    const float* f_y = (const float*)d_in[2];
    const float* w   = (const float*)d_in[3];
    const float* W1  = (const float*)d_in[4];
    const float* b1  = (const float*)d_in[5];
    const float* W2  = (const float*)d_in[6];
    const float* b2  = (const float*)d_in[7];
    const int*   nbr = (const int*)d_in[8];
    float* out = (float*)d_out;

    // Single dispatch. 2048 blocks: 256 per batch (16 rows/block),
    // batch = blk & 7 -> XCD pin.
    dim3 grid(B_ * M_ / 16), block(256);
    hipLaunchKernelGGL(it_kernel, grid, block, 0, stream,
                       y, x, f_y, w, W1, b1, W2, b2, nbr, out);
}